// Round 8
// baseline (114.139 us; speedup 1.0000x reference)
//
#include <hip/hip_runtime.h>

// SegmentMM: out[i] = A[i] (1x64) @ B_eff[segA[i]] (64x64), N=131072, K=M=64, S=128.
// segment_id_A sorted; B_eff[segB[j]] = B[j].
//
// Round-6: in-flight-bytes fix. Round-5 kernel (~40us) was latency-bound:
// only ~1KB/wave outstanding vs 10B/cyc/CU needed (Little's law). Now:
//  - RPW=64 (4 tiles/wave); ALL loads (64 B-dwords + 16 A-dwordx4) issued
//    straight-line before any conversion -> ~20KB in flight per wave.
//  - MFMA operands SWAPPED: acc = mfma(Bfrag, Afrag, acc). D col(lane&15) =
//    output row, D row(kg*4+reg) = 4 consecutive output cols -> one dwordx4
//    store per lane per 16x16 tile; lanes {n,n+16,n+32,n+48} cover full 64B
//    lines. (Layout symmetry of 16x16x32: A/B fragments have identical
//    index structure; round-5's unswapped version passed = layout verified.)
//  - Boundary waves (seg change inside 64 rows, <=127/2048) take a per-tile
//    slow path; boundary tiles use per-row fp32.

typedef float f32x4 __attribute__((ext_vector_type(4)));
typedef short s16x8 __attribute__((ext_vector_type(8)));

#define WPB 4    // waves per block
#define RPW 64   // rows per wave (4 MFMA tiles)

__global__ void build_inv_kernel(const int* __restrict__ segB, int* __restrict__ inv, int S) {
    int j = threadIdx.x + blockIdx.x * blockDim.x;
    if (j < S) inv[segB[j]] = j;
}

__device__ __forceinline__ short f2bf(float f) {  // RNE f32 -> bf16 bits
    unsigned u = __builtin_bit_cast(unsigned, f);
    u += 0x7fffu + ((u >> 16) & 1u);
    return (short)(u >> 16);
}

__global__ __launch_bounds__(256, 2) void segmm_mfma(
        const float* __restrict__ A,     // [N,64]
        const float* __restrict__ B,     // [S,64,64]
        const int*   __restrict__ segA,  // [N] sorted
        const int*   __restrict__ inv,   // [S] inverse of segment_id_B
        float*       __restrict__ out,   // [N,64]
        int nrows) {
    const int lane = threadIdx.x & 63;
    const int n16  = lane & 15;   // output row within tile / B col within 16
    const int kg   = lane >> 4;   // 0..3

    int w  = blockIdx.x * WPB + (threadIdx.x >> 6);
    int r0 = __builtin_amdgcn_readfirstlane(w * RPW);
    if (r0 >= nrows) return;

    const bool whole = (r0 + RPW <= nrows);
    const int  sFirst = __builtin_amdgcn_readfirstlane(segA[r0]);
    const int  sLast  = whole ? __builtin_amdgcn_readfirstlane(segA[r0 + RPW - 1]) : -1;

    if (whole && sFirst == sLast) {
        // ---------- fast path: one segment for all 64 rows ----------
        const int j = __builtin_amdgcn_readfirstlane(inv[sFirst]);

        // Issue ALL B loads (64 dwords; each instr = 4 full 64B lines).
        const float* __restrict__ bbase = B + (size_t)j * 4096 + n16;
        float br[4][2][8];
        #pragma unroll
        for (int ct = 0; ct < 4; ++ct)
            #pragma unroll
            for (int ks = 0; ks < 2; ++ks)
                #pragma unroll
                for (int i = 0; i < 8; ++i)
                    br[ct][ks][i] = bbase[(size_t)(kg * 8 + i + ks * 32) * 64 + ct * 16];

        // Issue ALL A loads (16 dwordx4).
        const float* __restrict__ abase = A + (size_t)(r0 + n16) * 64 + kg * 8;
        f32x4 ar[4][2][2];
        #pragma unroll
        for (int t = 0; t < 4; ++t)
            #pragma unroll
            for (int ks = 0; ks < 2; ++ks)
                #pragma unroll
                for (int h = 0; h < 2; ++h)
                    ar[t][ks][h] = *(const f32x4*)(abase + t * 1024 + ks * 32 + h * 4);

        // Convert B -> 8 bf16 fragments.
        s16x8 bfr[4][2];
        #pragma unroll
        for (int ct = 0; ct < 4; ++ct)
            #pragma unroll
            for (int ks = 0; ks < 2; ++ks)
                #pragma unroll
                for (int i = 0; i < 8; ++i)
                    bfr[ct][ks][i] = f2bf(br[ct][ks][i]);

        // Convert A -> 8 bf16 fragments.
        s16x8 af[4][2];
        #pragma unroll
        for (int t = 0; t < 4; ++t)
            #pragma unroll
            for (int ks = 0; ks < 2; ++ks) {
                #pragma unroll
                for (int i = 0; i < 4; ++i) {
                    af[t][ks][i]     = f2bf(ar[t][ks][0][i]);
                    af[t][ks][i + 4] = f2bf(ar[t][ks][1][i]);
                }
            }

        // MFMA + coalesced dwordx4 stores.
        #pragma unroll
        for (int t = 0; t < 4; ++t) {
            #pragma unroll
            for (int ct = 0; ct < 4; ++ct) {
                f32x4 acc = {0.f, 0.f, 0.f, 0.f};
                acc = __builtin_amdgcn_mfma_f32_16x16x32_bf16(bfr[ct][0], af[t][0], acc, 0, 0, 0);
                acc = __builtin_amdgcn_mfma_f32_16x16x32_bf16(bfr[ct][1], af[t][1], acc, 0, 0, 0);
                *(f32x4*)(out + (size_t)(r0 + t * 16 + n16) * 64 + ct * 16 + kg * 4) = acc;
            }
        }
    } else {
        // ---------- slow path: per-tile handling ----------
        int j_cur = -1;
        s16x8 bfr[4][2];
        for (int t = 0; t < RPW / 16; ++t) {
            const int rt = r0 + 16 * t;
            if (rt >= nrows) break;
            const bool full = (rt + 16 <= nrows);
            const int sa = __builtin_amdgcn_readfirstlane(segA[rt]);
            const int sb = full ? __builtin_amdgcn_readfirstlane(segA[rt + 15]) : -1;

            if (full && sa == sb) {
                const int j = __builtin_amdgcn_readfirstlane(inv[sa]);
                if (j != j_cur) {
                    j_cur = j;
                    const float* __restrict__ bbase = B + (size_t)j * 4096 + n16;
                    #pragma unroll
                    for (int ct = 0; ct < 4; ++ct)
                        #pragma unroll
                        for (int ks = 0; ks < 2; ++ks) {
                            float tmp[8];
                            #pragma unroll
                            for (int i = 0; i < 8; ++i)
                                tmp[i] = bbase[(size_t)(kg * 8 + i + ks * 32) * 64 + ct * 16];
                            #pragma unroll
                            for (int i = 0; i < 8; ++i)
                                bfr[ct][ks][i] = f2bf(tmp[i]);
                        }
                }
                const float* __restrict__ ap = A + (size_t)(rt + n16) * 64 + kg * 8;
                s16x8 af0, af1;
                {
                    f32x4 lo  = *(const f32x4*)(ap);
                    f32x4 hi  = *(const f32x4*)(ap + 4);
                    f32x4 lo2 = *(const f32x4*)(ap + 32);
                    f32x4 hi2 = *(const f32x4*)(ap + 36);
                    #pragma unroll
                    for (int i = 0; i < 4; ++i) {
                        af0[i]     = f2bf(lo[i]);
                        af0[i + 4] = f2bf(hi[i]);
                        af1[i]     = f2bf(lo2[i]);
                        af1[i + 4] = f2bf(hi2[i]);
                    }
                }
                #pragma unroll
                for (int ct = 0; ct < 4; ++ct) {
                    f32x4 acc = {0.f, 0.f, 0.f, 0.f};
                    acc = __builtin_amdgcn_mfma_f32_16x16x32_bf16(bfr[ct][0], af0, acc, 0, 0, 0);
                    acc = __builtin_amdgcn_mfma_f32_16x16x32_bf16(bfr[ct][1], af1, acc, 0, 0, 0);
                    *(f32x4*)(out + (size_t)(rt + n16) * 64 + ct * 16 + kg * 4) = acc;
                }
            } else {
                // segment boundary inside tile (rare): per-row fp32
                const int rEnd = full ? rt + 16 : nrows;
                for (int r = rt; r < rEnd; ++r) {
                    const int s = __builtin_amdgcn_readfirstlane(segA[r]);
                    const int j = __builtin_amdgcn_readfirstlane(inv[s]);
                    const float* __restrict__ ap = A + (size_t)r * 64;
                    const float* __restrict__ bp = B + (size_t)j * 4096 + lane;
                    float a0 = 0.f, a1 = 0.f, a2 = 0.f, a3 = 0.f;
                    #pragma unroll
                    for (int k = 0; k < 64; k += 4) {
                        a0 = fmaf(ap[k + 0], bp[(size_t)(k + 0) * 64], a0);
                        a1 = fmaf(ap[k + 1], bp[(size_t)(k + 1) * 64], a1);
                        a2 = fmaf(ap[k + 2], bp[(size_t)(k + 2) * 64], a2);
                        a3 = fmaf(ap[k + 3], bp[(size_t)(k + 3) * 64], a3);
                    }
                    out[(size_t)r * 64 + lane] = (a0 + a1) + (a2 + a3);
                }
                j_cur = -1;  // bfr no longer matches after boundary
            }
        }
    }
}

extern "C" void kernel_launch(void* const* d_in, const int* in_sizes, int n_in,
                              void* d_out, int out_size, void* d_ws, size_t ws_size,
                              hipStream_t stream) {
    const float* A    = (const float*)d_in[0];
    const float* B    = (const float*)d_in[1];
    const int*   segA = (const int*)d_in[2];
    const int*   segB = (const int*)d_in[3];
    float*       out  = (float*)d_out;
    int*         inv  = (int*)d_ws;   // S ints of scratch

    const int K = 64;
    const int N = in_sizes[0] / K;    // 131072
    const int S = in_sizes[3];        // 128

    build_inv_kernel<<<(S + 127) / 128, 128, 0, stream>>>(segB, inv, S);

    int waves  = (N + RPW - 1) / RPW;          // 2048
    int blocks = (waves + WPB - 1) / WPB;      // 512
    segmm_mfma<<<blocks, 256, 0, stream>>>(A, B, segA, inv, out, N);
}